// Round 19
// baseline (93.559 us; speedup 1.0000x reference)
//
#include <hip/hip_runtime.h>
#include <hip/hip_bf16.h>

typedef __attribute__((ext_vector_type(8))) short bf16x8;
typedef __attribute__((ext_vector_type(4))) float f32x4;

#define MFMA16(a,b,c) __builtin_amdgcn_mfma_f32_16x16x32_bf16((a),(b),(c),0,0,0)

static __device__ __forceinline__ unsigned short f2bf(float f) {
    unsigned int u = __builtin_bit_cast(unsigned int, f);
    u += 0x7fffu + ((u >> 16) & 1u);
    return (unsigned short)(u >> 16);
}

// async global->LDS, 16B per lane. LDS dest must be wave-uniform; HW adds lane*16.
static __device__ __forceinline__ void g2l16(const unsigned short* g, unsigned short* l) {
    __builtin_amdgcn_global_load_lds(
        (const __attribute__((address_space(1))) unsigned int*)g,
        (__attribute__((address_space(3))) unsigned int*)l,
        16, 0, 0);
}

// Problem constants (B=2, T=2048, D=2048, d=1024, kv=64)
#define BT     4096
#define DFULL  2048
#define DACT   1024
#define DKV    64
#define NSEL   512
#define TSEQ   2048
#define PADR   72

// ---------------------------------------------------------------------------
// Kernel 1: xs -> bf16, selected W rows/cols -> bf16 (zero-fill lives in oproj)
// ---------------------------------------------------------------------------
__global__ __launch_bounds__(256) void prep_kernel(
    const float* __restrict__ x,  const float* __restrict__ Wq,
    const float* __restrict__ Wk, const float* __restrict__ Wv,
    const float* __restrict__ Wo,
    unsigned short* __restrict__ xb,  unsigned short* __restrict__ Wqb,
    unsigned short* __restrict__ Wkb, unsigned short* __restrict__ Wvb,
    unsigned short* __restrict__ Wob)
{
    const int NA = (BT * DACT) / 8;
    const int NB = (NSEL * DACT) / 8;
    const int NC = (DACT * NSEL) / 8;
    const int TOT = NA + 3 * NB + NC;
    for (int u = blockIdx.x * blockDim.x + threadIdx.x; u < TOT;
         u += gridDim.x * blockDim.x) {
        if (u < NA) {
            int e = u * 8; int row = e >> 10, col = e & 1023;
            const float* s = x + (size_t)row * DFULL + col;
            f32x4 v0 = *(const f32x4*)s, v1 = *(const f32x4*)(s + 4);
            bf16x8 o;
            #pragma unroll
            for (int j = 0; j < 4; ++j) { o[j] = (short)f2bf(v0[j]); o[4+j] = (short)f2bf(v1[j]); }
            *(bf16x8*)(xb + e) = o;
        } else if (u < NA + 3 * NB) {
            int t = u - NA; int mat = t / NB; int q = t % NB;
            int e = q * 8; int n = e >> 10, c = e & 1023;
            const float* W = (mat == 0) ? Wq : (mat == 1) ? Wk : Wv;
            unsigned short* Wb = (mat == 0) ? Wqb : (mat == 1) ? Wkb : Wvb;
            int wrow = (n >> 6) * 128 + (n & 63);
            const float* s = W + (size_t)wrow * DFULL + c;
            f32x4 v0 = *(const f32x4*)s, v1 = *(const f32x4*)(s + 4);
            bf16x8 o;
            #pragma unroll
            for (int j = 0; j < 4; ++j) { o[j] = (short)f2bf(v0[j]); o[4+j] = (short)f2bf(v1[j]); }
            *(bf16x8*)(Wb + e) = o;
        } else {
            int q = u - NA - 3 * NB;
            int e = q * 8; int r = e >> 9, cs = e & 511;
            int col = (cs >> 6) * 128 + (cs & 63);
            const float* s = Wo + (size_t)r * DFULL + col;
            f32x4 v0 = *(const f32x4*)s, v1 = *(const f32x4*)(s + 4);
            bf16x8 o;
            #pragma unroll
            for (int j = 0; j < 4; ++j) { o[j] = (short)f2bf(v0[j]); o[4+j] = (short)f2bf(v1[j]); }
            *(bf16x8*)(Wob + e) = o;
        }
    }
}

// ---------------------------------------------------------------------------
// Kernel 2: unified QKV GEMM  C[4096,1536] = xb[4096,1024] . Wall[1536,1024]^T
// 64x128 tiles; grid (12 n-tiles FASTEST, 64 m-tiles) = 768 blocks, 3/CU
// uniform (confirmed-best round-14 configuration).
// K written feature-swizzled (j ^= (t&7)<<3); V written tiled+swizzled V^T.
// ---------------------------------------------------------------------------
__global__ __launch_bounds__(256) void qkv_gemm(
    const unsigned short* __restrict__ xb,
    const unsigned short* __restrict__ Wall,
    unsigned short* __restrict__ Qb, unsigned short* __restrict__ Kb,
    unsigned short* __restrict__ Vtb)
{
    __shared__ unsigned short As[64 * 64];
    __shared__ unsigned short Bs[128 * 64];
    const int m0 = blockIdx.y * 64, n0 = blockIdx.x * 128;
    const int tid = threadIdx.x, w = tid >> 6, l = tid & 63;
    const int lr = l & 15, g = l >> 4, lk = g * 8;
    const int wr = w >> 1, wc = w & 1;
    const int srow = l >> 3, scol = (l & 7) * 8;

    f32x4 acc[2][4] = {};
    for (int k0 = 0; k0 < DACT; k0 += 64) {
        __syncthreads();
        #pragma unroll
        for (int i = 0; i < 2; ++i) {
            int chunk = w * 2 + i;
            int row = chunk * 8 + srow;
            g2l16(&xb[(size_t)(m0 + row) * DACT + k0 + scol], &As[chunk * 512]);
        }
        #pragma unroll
        for (int i = 0; i < 4; ++i) {
            int chunk = w * 4 + i;
            int row = chunk * 8 + srow;
            g2l16(&Wall[(size_t)(n0 + row) * DACT + k0 + scol], &Bs[chunk * 512]);
        }
        __syncthreads();
        #pragma unroll
        for (int kk = 0; kk < 64; kk += 32) {
            bf16x8 a[2], b[4];
            #pragma unroll
            for (int m = 0; m < 2; ++m)
                a[m] = *(const bf16x8*)&As[(wr * 32 + m * 16 + lr) * 64 + kk + lk];
            #pragma unroll
            for (int n = 0; n < 4; ++n)
                b[n] = *(const bf16x8*)&Bs[(wc * 64 + n * 16 + lr) * 64 + kk + lk];
            #pragma unroll
            for (int m = 0; m < 2; ++m)
                #pragma unroll
                for (int n = 0; n < 4; ++n)
                    acc[m][n] = MFMA16(a[m], b[n], acc[m][n]);
        }
    }
    #pragma unroll
    for (int m = 0; m < 2; ++m)
        #pragma unroll
        for (int n = 0; n < 4; ++n)
            #pragma unroll
            for (int i = 0; i < 4; ++i) {
                int row = m0 + wr * 32 + m * 16 + g * 4 + i;
                int col = n0 + wc * 64 + n * 16 + lr;
                int mat = col >> 9, r = col & 511, h = r >> 6, j = r & 63;
                int bb = row >> 11, t = row & 2047, bh = bb * 8 + h;
                float v = acc[m][n][i];
                if (mat == 0)
                    Qb[((size_t)bh * TSEQ + t) * DKV + j] = f2bf(v * 0.125f);
                else if (mat == 1)
                    Kb[((size_t)bh * TSEQ + t) * DKV + (j ^ ((t & 7) << 3))] = f2bf(v);
                else
                    Vtb[(((size_t)bh * 32 + (t >> 6)) * 64 + j) * 64 +
                        ((t & 63) ^ ((j & 7) << 3))] = f2bf(v);
            }
}

// ---------------------------------------------------------------------------
// Kernel 3: causal attention — LDS-staged + SPLIT-K-2, FINE-GRAINED BLOCKS:
// 256 thr / 4 waves = 2 q-subtiles (16 rows) x 2 kv-parities per 32-row
// q-tile. LDS = KV dbuf 32KB + Ps 8KB = 40960B -> EXACTLY 4 blocks/CU:
// 4 independent barrier domains per CU (vs 2 with 512-thr blocks) and
// 4-wave barrier scope -> less straggle, same waves/SIMD.
// 4-deep zigzag: CU gets Q = {63-pi, 47-pi, pi, pi+16}; sum ntt = 67 const.
// Max-free softmax (0.125 Q-scale + __expf + f2bf); den via ones-MFMA;
// 2-way parity merge in LDS aliased over dead KV.
// ---------------------------------------------------------------------------
__global__ __launch_bounds__(256, 4) void attn_kernel(
    const unsigned short* __restrict__ Qb,
    const unsigned short* __restrict__ Kb,    // feature-swizzled
    const unsigned short* __restrict__ Vtb,   // tiled + swizzled
    unsigned short* __restrict__ att)
{
    __shared__ unsigned short KV[2][2][2][2048]; // [buf][parity][K|V][32x64... half-tile? no: 64x64/2]
    // NOTE: region [b][par][kv] holds HALF a 64x64 tile? No — layout below:
    // each (par, kv) region is 2048 shorts = half of one 4096-short tile;
    // the two halves of tile t live in [b][par][0] (K halves staged by the
    // SAME wave across two 1024-short sub-blocks). See STAGE.
    __shared__ unsigned short KV2[2][2][2][2048]; // second half of each tile
    __shared__ unsigned short Ps[4][16 * 64];     // 8KB, XOR-swizzled rows
    const int f = blockIdx.x;
    const int k = f & 511, bh = k & 15, pi = k >> 4;      // pi in [0,32)
    const int Q = (f < 512) ? (63 - pi) : pi;             // 32-row q-tile idx
    const int ntt = (Q >> 1) + 1;            // kv-tiles (diag at ntt-1)
    const int np = (ntt + 1) >> 1;           // staged pairs
    const int tid = threadIdx.x, w = tid >> 6, l = tid & 63;
    const int lr = l & 15, g = l >> 4, lk = g * 8;
    const int s = w >> 1, j = w & 1;         // q-subtile, kv-parity
    const size_t kvb = (size_t)bh * TSEQ * DKV;
    const int bb = bh >> 3, h = bh & 7;
    const int qs0 = Q * 32 + s * 16;

    unsigned short* Psw = Ps[w];
    const short os = (short)0x3F80;          // bf16 1.0
    const bf16x8 ones = {os, os, os, os, os, os, os, os};

    bf16x8 qf0 = *(const bf16x8*)&Qb[kvb + (size_t)(qs0 + lr) * DKV + lk];
    bf16x8 qf1 = *(const bf16x8*)&Qb[kvb + (size_t)(qs0 + lr) * DKV + 32 + lk];

    f32x4 acc[4] = {};
    f32x4 dacc = {};

    // stage pair p into buffer b: wave w owns region (par_=w>>1, kv_=w&1),
    // copying a FULL 4096-short tile as two 2048-short halves (KV, KV2).
    #define STAGE(b, p)                                                        \
        do {                                                                   \
            int par_ = w >> 1, kv_ = w & 1;                                    \
            int t_ = 2 * (p) + par_;                                           \
            if (t_ < ntt) {                                                    \
                const unsigned short* src_ =                                   \
                    (kv_ ? Vtb : Kb) + kvb + (size_t)t_ * 4096;                \
                unsigned short* d0_ = KV[b][par_][kv_];                        \
                unsigned short* d1_ = KV2[b][par_][kv_];                       \
                g2l16(&src_[l * 8],        d0_);                               \
                g2l16(&src_[512 + l * 8],  d0_ + 512);                         \
                g2l16(&src_[1024 + l * 8], d0_ + 1024);                        \
                g2l16(&src_[1536 + l * 8], d0_ + 1536);                        \
                g2l16(&src_[2048 + l * 8], d1_);                               \
                g2l16(&src_[2560 + l * 8], d1_ + 512);                         \
                g2l16(&src_[3072 + l * 8], d1_ + 1024);                        \
                g2l16(&src_[3584 + l * 8], d1_ + 1536);                        \
            }                                                                  \
        } while (0)

    STAGE(0, 0);
    __syncthreads();

    for (int p = 0; p < np; ++p) {
        const int cur = p & 1;
        if (p + 1 < np) STAGE(cur ^ 1, p + 1);

        const int jt = 2 * p + j;
        if (jt < ntt) {
            const unsigned short* Kt0 = KV[cur][j][0];   // rows 0..31
            const unsigned short* Kt1 = KV2[cur][j][0];  // rows 32..63
            const unsigned short* Vt0 = KV[cur][j][1];
            const unsigned short* Vt1 = KV2[cur][j][1];

            #pragma unroll
            for (int c = 0; c < 4; ++c) {
                const int row = c * 16 + lr, sr = (row & 7) << 3;
                const unsigned short* Kt = (row < 32) ? Kt0 : Kt1;
                const int rrow = row & 31;
                bf16x8 b0 = *(const bf16x8*)&Kt[rrow * 64 + (lk ^ sr)];
                bf16x8 b1 = *(const bf16x8*)&Kt[rrow * 64 + ((32 + lk) ^ sr)];
                f32x4 z = {};
                z = MFMA16(qf0, b0, z);
                z = MFMA16(qf1, b1, z);
                if (jt == ntt - 1) {
                    int kcol = jt * 64 + c * 16 + lr;
                    #pragma unroll
                    for (int i = 0; i < 4; ++i)
                        if (kcol > qs0 + g * 4 + i) z[i] = -64.f;
                }
                const int colp = c * 16 + lr;
                #pragma unroll
                for (int i = 0; i < 4; ++i) {
                    const int prow = g * 4 + i;
                    Psw[prow * 64 + (colp ^ ((prow & 7) << 3))] =
                        f2bf(__expf(z[i]));
                }
            }
            const int psr = (lr & 7) << 3;
            bf16x8 pa0 = *(const bf16x8*)&Psw[lr * 64 + (lk ^ psr)];
            bf16x8 pa1 = *(const bf16x8*)&Psw[lr * 64 + ((32 + lk) ^ psr)];

            #pragma unroll
            for (int n = 0; n < 4; ++n) {
                const int row = n * 16 + lr, sr = (row & 7) << 3;
                const unsigned short* Vt = (row < 32) ? Vt0 : Vt1;
                const int rrow = row & 31;
                bf16x8 v0 = *(const bf16x8*)&Vt[rrow * 64 + (lk ^ sr)];
                bf16x8 v1 = *(const bf16x8*)&Vt[rrow * 64 + ((32 + lk) ^ sr)];
                acc[n] = MFMA16(pa0, v0, acc[n]);
                acc[n] = MFMA16(pa1, v1, acc[n]);
            }
            dacc = MFMA16(pa0, ones, dacc);
            dacc = MFMA16(pa1, ones, dacc);
        }
        __syncthreads();
    }
    #undef STAGE

    // ---- 2-way merge (parity partials) in LDS aliased over dead KV ----
    float* M = (float*)KV;                   // [2][1088]: 16x64 acc + 16 den
    if (j == 1) {
        #pragma unroll
        for (int n = 0; n < 4; ++n)
            #pragma unroll
            for (int i = 0; i < 4; ++i)
                M[s * 1088 + (g * 4 + i) * 64 + n * 16 + lr] = acc[n][i];
        if (lr == 0) {
            #pragma unroll
            for (int i = 0; i < 4; ++i)
                M[s * 1088 + 1024 + g * 4 + i] = dacc[i];
        }
    }
    __syncthreads();
    if (j == 0) {
        #pragma unroll
        for (int i = 0; i < 4; ++i) {
            float den = dacc[i] + M[s * 1088 + 1024 + g * 4 + i];
            float inv = 1.0f / den;
            int t = qs0 + g * 4 + i;
            #pragma unroll
            for (int n = 0; n < 4; ++n) {
                float v = acc[n][i] + M[s * 1088 + (g * 4 + i) * 64 + n * 16 + lr];
                att[((size_t)bb * TSEQ + t) * NSEL + h * 64 + n * 16 + lr] =
                    f2bf(v * inv);
            }
        }
    }
}

// ---------------------------------------------------------------------------
// Kernel 4: output projection  out[4096,1024] = att[4096,512] . Wob[1024,512]^T
// grid (16 n FASTEST, 32 m): x<8 = compute tile; x>=8 = zero-fill tile of
// the padded right half (absorbed from prep — overlaps with compute blocks).
// ---------------------------------------------------------------------------
__global__ __launch_bounds__(256) void oproj_gemm(
    const unsigned short* __restrict__ att,
    const unsigned short* __restrict__ Wob,
    float* __restrict__ out)
{
    const int tid = threadIdx.x;
    if (blockIdx.x >= 8) {
        // zero tile: 128 rows x 128 cols f32 in the padded half
        const int m0z = blockIdx.y * 128;
        const int n0z = DACT + (blockIdx.x - 8) * 128;
        const f32x4 z = {0.f, 0.f, 0.f, 0.f};
        #pragma unroll
        for (int i = 0; i < 16; ++i) {
            int chunk = tid + i * 256;            // 4096 chunks of 16B
            int row = chunk >> 5, c = (chunk & 31) * 4;
            *(f32x4*)&out[(size_t)(m0z + row) * DFULL + n0z + c] = z;
        }
        return;
    }
    __shared__ unsigned short As[128 * 64];
    __shared__ unsigned short Bs[128 * 64];
    const int m0 = blockIdx.y * 128, n0 = blockIdx.x * 128;
    const int w = tid >> 6, l = tid & 63;
    const int lr = l & 15, g = l >> 4, lk = g * 8;
    const int wr = w >> 1, wc = w & 1;
    const int srow = l >> 3, scol = (l & 7) * 8;

    f32x4 acc[4][4] = {};
    for (int k0 = 0; k0 < NSEL; k0 += 64) {
        __syncthreads();
        #pragma unroll
        for (int i = 0; i < 4; ++i) {
            int chunk = w * 4 + i;
            int row = chunk * 8 + srow;
            g2l16(&att[(size_t)(m0 + row) * NSEL + k0 + scol], &As[chunk * 512]);
            g2l16(&Wob[(size_t)(n0 + row) * NSEL + k0 + scol], &Bs[chunk * 512]);
        }
        __syncthreads();
        #pragma unroll
        for (int kk = 0; kk < 64; kk += 32) {
            bf16x8 a[4], b[4];
            #pragma unroll
            for (int m = 0; m < 4; ++m)
                a[m] = *(const bf16x8*)&As[(wr * 64 + m * 16 + lr) * 64 + kk + lk];
            #pragma unroll
            for (int n = 0; n < 4; ++n)
                b[n] = *(const bf16x8*)&Bs[(wc * 64 + n * 16 + lr) * 64 + kk + lk];
            #pragma unroll
            for (int m = 0; m < 4; ++m)
                #pragma unroll
                for (int n = 0; n < 4; ++n)
                    acc[m][n] = MFMA16(a[m], b[n], acc[m][n]);
        }
    }
    #pragma unroll
    for (int m = 0; m < 4; ++m)
        #pragma unroll
        for (int n = 0; n < 4; ++n)
            #pragma unroll
            for (int i = 0; i < 4; ++i) {
                int row = m0 + wr * 64 + m * 16 + g * 4 + i;
                int col = n0 + wc * 64 + n * 16 + lr;
                out[(size_t)row * DFULL + col] = acc[m][n][i];
            }
}

// ---------------------------------------------------------------------------
extern "C" void kernel_launch(void* const* d_in, const int* in_sizes, int n_in,
                              void* d_out, int out_size, void* d_ws, size_t ws_size,
                              hipStream_t stream) {
    const float* x  = (const float*)d_in[0];
    const float* Wq = (const float*)d_in[1];
    const float* Wk = (const float*)d_in[2];
    const float* Wv = (const float*)d_in[3];
    const float* Wo = (const float*)d_in[4];
    float* out = (float*)d_out;

    char* ws = (char*)d_ws;
    unsigned short* xb  = (unsigned short*)(ws);                    // 8 MB
    unsigned short* Wqb = (unsigned short*)(ws + 8388608);          // 1 MB each,
    unsigned short* Wkb = (unsigned short*)(ws + 9437184);          // contiguous = Wall
    unsigned short* Wvb = (unsigned short*)(ws + 10485760);
    unsigned short* Wob = (unsigned short*)(ws + 11534336);         // 1 MB
    unsigned short* Qb  = (unsigned short*)(ws + 12582912);         // 4 MB
    unsigned short* Kb  = (unsigned short*)(ws + 16777216);         // 4 MB (swizzled)
    unsigned short* Vtb = (unsigned short*)(ws + 20971520);         // 4 MB (tiled+swz)
    unsigned short* att = (unsigned short*)(ws + 25165824);         // 4 MB

    prep_kernel<<<2048, 256, 0, stream>>>(x, Wq, Wk, Wv, Wo,
                                          xb, Wqb, Wkb, Wvb, Wob);
    qkv_gemm<<<dim3(12, 64), 256, 0, stream>>>(xb, Wqb, Qb, Kb, Vtb);
    attn_kernel<<<1024, 256, 0, stream>>>(Qb, Kb, Vtb, att);
    oproj_gemm<<<dim3(16, 32), 256, 0, stream>>>(att, Wob, out);
}

// Round 20
// 82.043 us; speedup vs baseline: 1.1404x; 1.1404x over previous
//
#include <hip/hip_runtime.h>
#include <hip/hip_bf16.h>

typedef __attribute__((ext_vector_type(8))) short bf16x8;
typedef __attribute__((ext_vector_type(4))) float f32x4;

#define MFMA16(a,b,c) __builtin_amdgcn_mfma_f32_16x16x32_bf16((a),(b),(c),0,0,0)

static __device__ __forceinline__ unsigned short f2bf(float f) {
    unsigned int u = __builtin_bit_cast(unsigned int, f);
    u += 0x7fffu + ((u >> 16) & 1u);
    return (unsigned short)(u >> 16);
}

// async global->LDS, 16B per lane. LDS dest must be wave-uniform; HW adds lane*16.
static __device__ __forceinline__ void g2l16(const unsigned short* g, unsigned short* l) {
    __builtin_amdgcn_global_load_lds(
        (const __attribute__((address_space(1))) unsigned int*)g,
        (__attribute__((address_space(3))) unsigned int*)l,
        16, 0, 0);
}

// Problem constants (B=2, T=2048, D=2048, d=1024, kv=64)
#define BT     4096
#define DFULL  2048
#define DACT   1024
#define DKV    64
#define NSEL   512
#define TSEQ   2048
#define PADR   72

// ---------------------------------------------------------------------------
// Kernel 1: xs -> bf16, selected W rows/cols -> bf16 (zero-fill lives in oproj)
// ---------------------------------------------------------------------------
__global__ __launch_bounds__(256) void prep_kernel(
    const float* __restrict__ x,  const float* __restrict__ Wq,
    const float* __restrict__ Wk, const float* __restrict__ Wv,
    const float* __restrict__ Wo,
    unsigned short* __restrict__ xb,  unsigned short* __restrict__ Wqb,
    unsigned short* __restrict__ Wkb, unsigned short* __restrict__ Wvb,
    unsigned short* __restrict__ Wob)
{
    const int NA = (BT * DACT) / 8;
    const int NB = (NSEL * DACT) / 8;
    const int NC = (DACT * NSEL) / 8;
    const int TOT = NA + 3 * NB + NC;
    for (int u = blockIdx.x * blockDim.x + threadIdx.x; u < TOT;
         u += gridDim.x * blockDim.x) {
        if (u < NA) {
            int e = u * 8; int row = e >> 10, col = e & 1023;
            const float* s = x + (size_t)row * DFULL + col;
            f32x4 v0 = *(const f32x4*)s, v1 = *(const f32x4*)(s + 4);
            bf16x8 o;
            #pragma unroll
            for (int j = 0; j < 4; ++j) { o[j] = (short)f2bf(v0[j]); o[4+j] = (short)f2bf(v1[j]); }
            *(bf16x8*)(xb + e) = o;
        } else if (u < NA + 3 * NB) {
            int t = u - NA; int mat = t / NB; int q = t % NB;
            int e = q * 8; int n = e >> 10, c = e & 1023;
            const float* W = (mat == 0) ? Wq : (mat == 1) ? Wk : Wv;
            unsigned short* Wb = (mat == 0) ? Wqb : (mat == 1) ? Wkb : Wvb;
            int wrow = (n >> 6) * 128 + (n & 63);
            const float* s = W + (size_t)wrow * DFULL + c;
            f32x4 v0 = *(const f32x4*)s, v1 = *(const f32x4*)(s + 4);
            bf16x8 o;
            #pragma unroll
            for (int j = 0; j < 4; ++j) { o[j] = (short)f2bf(v0[j]); o[4+j] = (short)f2bf(v1[j]); }
            *(bf16x8*)(Wb + e) = o;
        } else {
            int q = u - NA - 3 * NB;
            int e = q * 8; int r = e >> 9, cs = e & 511;
            int col = (cs >> 6) * 128 + (cs & 63);
            const float* s = Wo + (size_t)r * DFULL + col;
            f32x4 v0 = *(const f32x4*)s, v1 = *(const f32x4*)(s + 4);
            bf16x8 o;
            #pragma unroll
            for (int j = 0; j < 4; ++j) { o[j] = (short)f2bf(v0[j]); o[4+j] = (short)f2bf(v1[j]); }
            *(bf16x8*)(Wob + e) = o;
        }
    }
}

// ---------------------------------------------------------------------------
// Kernel 2: unified QKV GEMM  C[4096,1536] = xb[4096,1024] . Wall[1536,1024]^T
// 64x128 tiles; grid (12 n-tiles FASTEST, 64 m-tiles) = 768 blocks, 3/CU
// uniform (confirmed-best round-14 configuration).
// K written feature-swizzled (j ^= (t&7)<<3); V written tiled+swizzled V^T.
// ---------------------------------------------------------------------------
__global__ __launch_bounds__(256) void qkv_gemm(
    const unsigned short* __restrict__ xb,
    const unsigned short* __restrict__ Wall,
    unsigned short* __restrict__ Qb, unsigned short* __restrict__ Kb,
    unsigned short* __restrict__ Vtb)
{
    __shared__ unsigned short As[64 * 64];
    __shared__ unsigned short Bs[128 * 64];
    const int m0 = blockIdx.y * 64, n0 = blockIdx.x * 128;
    const int tid = threadIdx.x, w = tid >> 6, l = tid & 63;
    const int lr = l & 15, g = l >> 4, lk = g * 8;
    const int wr = w >> 1, wc = w & 1;
    const int srow = l >> 3, scol = (l & 7) * 8;

    f32x4 acc[2][4] = {};
    for (int k0 = 0; k0 < DACT; k0 += 64) {
        __syncthreads();
        #pragma unroll
        for (int i = 0; i < 2; ++i) {
            int chunk = w * 2 + i;
            int row = chunk * 8 + srow;
            g2l16(&xb[(size_t)(m0 + row) * DACT + k0 + scol], &As[chunk * 512]);
        }
        #pragma unroll
        for (int i = 0; i < 4; ++i) {
            int chunk = w * 4 + i;
            int row = chunk * 8 + srow;
            g2l16(&Wall[(size_t)(n0 + row) * DACT + k0 + scol], &Bs[chunk * 512]);
        }
        __syncthreads();
        #pragma unroll
        for (int kk = 0; kk < 64; kk += 32) {
            bf16x8 a[2], b[4];
            #pragma unroll
            for (int m = 0; m < 2; ++m)
                a[m] = *(const bf16x8*)&As[(wr * 32 + m * 16 + lr) * 64 + kk + lk];
            #pragma unroll
            for (int n = 0; n < 4; ++n)
                b[n] = *(const bf16x8*)&Bs[(wc * 64 + n * 16 + lr) * 64 + kk + lk];
            #pragma unroll
            for (int m = 0; m < 2; ++m)
                #pragma unroll
                for (int n = 0; n < 4; ++n)
                    acc[m][n] = MFMA16(a[m], b[n], acc[m][n]);
        }
    }
    #pragma unroll
    for (int m = 0; m < 2; ++m)
        #pragma unroll
        for (int n = 0; n < 4; ++n)
            #pragma unroll
            for (int i = 0; i < 4; ++i) {
                int row = m0 + wr * 32 + m * 16 + g * 4 + i;
                int col = n0 + wc * 64 + n * 16 + lr;
                int mat = col >> 9, r = col & 511, h = r >> 6, j = r & 63;
                int bb = row >> 11, t = row & 2047, bh = bb * 8 + h;
                float v = acc[m][n][i];
                if (mat == 0)
                    Qb[((size_t)bh * TSEQ + t) * DKV + j] = f2bf(v * 0.125f);
                else if (mat == 1)
                    Kb[((size_t)bh * TSEQ + t) * DKV + (j ^ ((t & 7) << 3))] = f2bf(v);
                else
                    Vtb[(((size_t)bh * 32 + (t >> 6)) * 64 + j) * 64 +
                        ((t & 63) ^ ((j & 7) << 3))] = f2bf(v);
            }
}

// ---------------------------------------------------------------------------
// Kernel 3: causal attention — SINGLE-BUFFERED pair staging, 256 thr / 4
// waves: wave = (q-subtile s, kv-parity j) on a 32-row q-tile. LDS =
// KV[2][2][4096] (one tile pair, 32KB) + Ps (8KB) = 40960B -> EXACTLY
// 4 blocks/CU = same 4 waves/SIMD as the confirmed-best config, but 4
// independent barrier domains and 4-wave barrier scope. Stage latency is
// intra-block exposed (2 barriers/step); cross-block TLP covers it.
// 4-deep zigzag; max-free softmax (0.125 scale + __expf + f2bf);
// den via ones-MFMA; 2-way parity merge in LDS aliased over dead KV.
// ---------------------------------------------------------------------------
__global__ __launch_bounds__(256, 4) void attn_kernel(
    const unsigned short* __restrict__ Qb,
    const unsigned short* __restrict__ Kb,    // feature-swizzled
    const unsigned short* __restrict__ Vtb,   // tiled + swizzled
    unsigned short* __restrict__ att)
{
    __shared__ unsigned short KV[2][2][4096]; // [parity][K|V][64x64] = 32KB (single pair)
    __shared__ unsigned short Ps[4][16 * 64]; // 8KB, XOR-swizzled rows
    const int f = blockIdx.x;
    const int k = f & 511, bh = k & 15, pi = k >> 4;      // pi in [0,32)
    const int Q = (f < 512) ? (63 - pi) : pi;             // 32-row q-tile idx
    const int ntt = (Q >> 1) + 1;            // kv-tiles (diag at ntt-1)
    const int np = (ntt + 1) >> 1;           // staged pairs
    const int tid = threadIdx.x, w = tid >> 6, l = tid & 63;
    const int lr = l & 15, g = l >> 4, lk = g * 8;
    const int s = w >> 1, j = w & 1;         // q-subtile, kv-parity
    const size_t kvb = (size_t)bh * TSEQ * DKV;
    const int bb = bh >> 3, h = bh & 7;
    const int qs0 = Q * 32 + s * 16;

    unsigned short* Psw = Ps[w];
    const short os = (short)0x3F80;          // bf16 1.0
    const bf16x8 ones = {os, os, os, os, os, os, os, os};

    bf16x8 qf0 = *(const bf16x8*)&Qb[kvb + (size_t)(qs0 + lr) * DKV + lk];
    bf16x8 qf1 = *(const bf16x8*)&Qb[kvb + (size_t)(qs0 + lr) * DKV + 32 + lk];

    f32x4 acc[4] = {};
    f32x4 dacc = {};

    // stage pair p: wave w owns region (par_=w>>1, kv_=w&1) = one full
    // 4096-short tile (8 x g2l16).
    #define STAGE(p)                                                           \
        do {                                                                   \
            int par_ = w >> 1, kv_ = w & 1;                                    \
            int t_ = 2 * (p) + par_;                                           \
            if (t_ < ntt) {                                                    \
                const unsigned short* src_ =                                   \
                    (kv_ ? Vtb : Kb) + kvb + (size_t)t_ * 4096;                \
                unsigned short* d_ = KV[par_][kv_];                            \
                g2l16(&src_[l * 8],        d_);                                \
                g2l16(&src_[512 + l * 8],  d_ + 512);                          \
                g2l16(&src_[1024 + l * 8], d_ + 1024);                         \
                g2l16(&src_[1536 + l * 8], d_ + 1536);                         \
                g2l16(&src_[2048 + l * 8], d_ + 2048);                         \
                g2l16(&src_[2560 + l * 8], d_ + 2560);                         \
                g2l16(&src_[3072 + l * 8], d_ + 3072);                         \
                g2l16(&src_[3584 + l * 8], d_ + 3584);                         \
            }                                                                  \
        } while (0)

    for (int p = 0; p < np; ++p) {
        __syncthreads();                      // prior pair fully consumed
        STAGE(p);
        __syncthreads();                      // staged (barrier drains vmcnt)

        const int jt = 2 * p + j;
        if (jt < ntt) {
            const unsigned short* Kt = KV[j][0];
            const unsigned short* Vt = KV[j][1];

            #pragma unroll
            for (int c = 0; c < 4; ++c) {
                const int row = c * 16 + lr, sr = (row & 7) << 3;
                bf16x8 b0 = *(const bf16x8*)&Kt[row * 64 + (lk ^ sr)];
                bf16x8 b1 = *(const bf16x8*)&Kt[row * 64 + ((32 + lk) ^ sr)];
                f32x4 z = {};
                z = MFMA16(qf0, b0, z);
                z = MFMA16(qf1, b1, z);
                if (jt == ntt - 1) {
                    int kcol = jt * 64 + c * 16 + lr;
                    #pragma unroll
                    for (int i = 0; i < 4; ++i)
                        if (kcol > qs0 + g * 4 + i) z[i] = -64.f;
                }
                const int colp = c * 16 + lr;
                #pragma unroll
                for (int i = 0; i < 4; ++i) {
                    const int prow = g * 4 + i;
                    Psw[prow * 64 + (colp ^ ((prow & 7) << 3))] =
                        f2bf(__expf(z[i]));
                }
            }
            const int psr = (lr & 7) << 3;
            bf16x8 pa0 = *(const bf16x8*)&Psw[lr * 64 + (lk ^ psr)];
            bf16x8 pa1 = *(const bf16x8*)&Psw[lr * 64 + ((32 + lk) ^ psr)];

            #pragma unroll
            for (int n = 0; n < 4; ++n) {
                const int row = n * 16 + lr, sr = (row & 7) << 3;
                bf16x8 v0 = *(const bf16x8*)&Vt[row * 64 + (lk ^ sr)];
                bf16x8 v1 = *(const bf16x8*)&Vt[row * 64 + ((32 + lk) ^ sr)];
                acc[n] = MFMA16(pa0, v0, acc[n]);
                acc[n] = MFMA16(pa1, v1, acc[n]);
            }
            dacc = MFMA16(pa0, ones, dacc);
            dacc = MFMA16(pa1, ones, dacc);
        }
    }
    #undef STAGE
    __syncthreads();                          // all compute done before aliasing KV

    // ---- 2-way merge (parity partials) in LDS aliased over dead KV ----
    float* M = (float*)KV;                   // [2][1088]: 16x64 acc + 16 den
    if (j == 1) {
        #pragma unroll
        for (int n = 0; n < 4; ++n)
            #pragma unroll
            for (int i = 0; i < 4; ++i)
                M[s * 1088 + (g * 4 + i) * 64 + n * 16 + lr] = acc[n][i];
        if (lr == 0) {
            #pragma unroll
            for (int i = 0; i < 4; ++i)
                M[s * 1088 + 1024 + g * 4 + i] = dacc[i];
        }
    }
    __syncthreads();
    if (j == 0) {
        #pragma unroll
        for (int i = 0; i < 4; ++i) {
            float den = dacc[i] + M[s * 1088 + 1024 + g * 4 + i];
            float inv = 1.0f / den;
            int t = qs0 + g * 4 + i;
            #pragma unroll
            for (int n = 0; n < 4; ++n) {
                float v = acc[n][i] + M[s * 1088 + (g * 4 + i) * 64 + n * 16 + lr];
                att[((size_t)bb * TSEQ + t) * NSEL + h * 64 + n * 16 + lr] =
                    f2bf(v * inv);
            }
        }
    }
}

// ---------------------------------------------------------------------------
// Kernel 4: output projection  out[4096,1024] = att[4096,512] . Wob[1024,512]^T
// grid (16 n FASTEST, 32 m): x<8 = compute tile; x>=8 = zero-fill tile of
// the padded right half (absorbed from prep — overlaps with compute blocks).
// ---------------------------------------------------------------------------
__global__ __launch_bounds__(256) void oproj_gemm(
    const unsigned short* __restrict__ att,
    const unsigned short* __restrict__ Wob,
    float* __restrict__ out)
{
    const int tid = threadIdx.x;
    if (blockIdx.x >= 8) {
        // zero tile: 128 rows x 128 cols f32 in the padded half
        const int m0z = blockIdx.y * 128;
        const int n0z = DACT + (blockIdx.x - 8) * 128;
        const f32x4 z = {0.f, 0.f, 0.f, 0.f};
        #pragma unroll
        for (int i = 0; i < 16; ++i) {
            int chunk = tid + i * 256;            // 4096 chunks of 16B
            int row = chunk >> 5, c = (chunk & 31) * 4;
            *(f32x4*)&out[(size_t)(m0z + row) * DFULL + n0z + c] = z;
        }
        return;
    }
    __shared__ unsigned short As[128 * 64];
    __shared__ unsigned short Bs[128 * 64];
    const int m0 = blockIdx.y * 128, n0 = blockIdx.x * 128;
    const int w = tid >> 6, l = tid & 63;
    const int lr = l & 15, g = l >> 4, lk = g * 8;
    const int wr = w >> 1, wc = w & 1;
    const int srow = l >> 3, scol = (l & 7) * 8;

    f32x4 acc[4][4] = {};
    for (int k0 = 0; k0 < NSEL; k0 += 64) {
        __syncthreads();
        #pragma unroll
        for (int i = 0; i < 4; ++i) {
            int chunk = w * 4 + i;
            int row = chunk * 8 + srow;
            g2l16(&att[(size_t)(m0 + row) * NSEL + k0 + scol], &As[chunk * 512]);
            g2l16(&Wob[(size_t)(n0 + row) * NSEL + k0 + scol], &Bs[chunk * 512]);
        }
        __syncthreads();
        #pragma unroll
        for (int kk = 0; kk < 64; kk += 32) {
            bf16x8 a[4], b[4];
            #pragma unroll
            for (int m = 0; m < 4; ++m)
                a[m] = *(const bf16x8*)&As[(wr * 64 + m * 16 + lr) * 64 + kk + lk];
            #pragma unroll
            for (int n = 0; n < 4; ++n)
                b[n] = *(const bf16x8*)&Bs[(wc * 64 + n * 16 + lr) * 64 + kk + lk];
            #pragma unroll
            for (int m = 0; m < 4; ++m)
                #pragma unroll
                for (int n = 0; n < 4; ++n)
                    acc[m][n] = MFMA16(a[m], b[n], acc[m][n]);
        }
    }
    #pragma unroll
    for (int m = 0; m < 4; ++m)
        #pragma unroll
        for (int n = 0; n < 4; ++n)
            #pragma unroll
            for (int i = 0; i < 4; ++i) {
                int row = m0 + wr * 64 + m * 16 + g * 4 + i;
                int col = n0 + wc * 64 + n * 16 + lr;
                out[(size_t)row * DFULL + col] = acc[m][n][i];
            }
}

// ---------------------------------------------------------------------------
extern "C" void kernel_launch(void* const* d_in, const int* in_sizes, int n_in,
                              void* d_out, int out_size, void* d_ws, size_t ws_size,
                              hipStream_t stream) {
    const float* x  = (const float*)d_in[0];
    const float* Wq = (const float*)d_in[1];
    const float* Wk = (const float*)d_in[2];
    const float* Wv = (const float*)d_in[3];
    const float* Wo = (const float*)d_in[4];
    float* out = (float*)d_out;

    char* ws = (char*)d_ws;
    unsigned short* xb  = (unsigned short*)(ws);                    // 8 MB
    unsigned short* Wqb = (unsigned short*)(ws + 8388608);          // 1 MB each,
    unsigned short* Wkb = (unsigned short*)(ws + 9437184);          // contiguous = Wall
    unsigned short* Wvb = (unsigned short*)(ws + 10485760);
    unsigned short* Wob = (unsigned short*)(ws + 11534336);         // 1 MB
    unsigned short* Qb  = (unsigned short*)(ws + 12582912);         // 4 MB
    unsigned short* Kb  = (unsigned short*)(ws + 16777216);         // 4 MB (swizzled)
    unsigned short* Vtb = (unsigned short*)(ws + 20971520);         // 4 MB (tiled+swz)
    unsigned short* att = (unsigned short*)(ws + 25165824);         // 4 MB

    prep_kernel<<<2048, 256, 0, stream>>>(x, Wq, Wk, Wv, Wo,
                                          xb, Wqb, Wkb, Wvb, Wob);
    qkv_gemm<<<dim3(12, 64), 256, 0, stream>>>(xb, Wqb, Qb, Kb, Vtb);
    attn_kernel<<<1024, 256, 0, stream>>>(Qb, Kb, Vtb, att);
    oproj_gemm<<<dim3(16, 32), 256, 0, stream>>>(att, Wob, out);
}